// Round 5
// baseline (256.747 us; speedup 1.0000x reference)
//
#include <hip/hip_runtime.h>

#define STEPS 100
#define BATCH 256
#define D1 784
#define D1P 785            // +1 zero row = padding target for gathers
#define D2 512
#define NSTEP 99           // computed steps t = 0..98 (output rows 1..99)
#define LIST_MAX 96        // capacity per (t,b); Binom(784,.05) max ~66

// ---- primary ws layout: Wt [D1P][D2] fp32 ++ z [NSTEP][BATCH][D2] fp32 ----
#define WT_BYTES  (D1P * D2 * 4)                       // 1,607,680
#define Z_OFF     ((size_t)((WT_BYTES + 255) & ~255))
#define Z_BYTES   ((size_t)NSTEP * BATCH * D2 * 4)     // 51,904,512
#define WS_NEEDED (Z_OFF + Z_BYTES)

// ---- fallback (R4) ws layout ----
#define LIST_PAD   80
#define NBLK_T     400
#define NBLK_C     (NSTEP * BATCH / 4)
#define CNT_OFF    WT_BYTES
#define CNT_BYTES  (NSTEP * BATCH * 4)
#define LIST_OFF   ((CNT_OFF + CNT_BYTES + 255) & ~255)
#define LIST_BYTES (NSTEP * BATCH * LIST_PAD * 4)
#define WS_NEEDED_FB ((size_t)(LIST_OFF + LIST_BYTES))

// ---------------- transpose W [D2][D1] -> Wt [D1P][D2], row 784 zeroed -------
__global__ void transpose_w(const float* __restrict__ W, float* __restrict__ Wt) {
    __shared__ float tile[32][33];
    int i0 = blockIdx.x * 32;
    int j0 = blockIdx.y * 32;
    int tx = threadIdx.x, ty = threadIdx.y;
    for (int r = 0; r < 32; r += 8) {
        int jj = j0 + ty + r, ii = i0 + tx;
        float v = 0.f;
        if (jj < D2 && ii < D1) v = W[jj * D1 + ii];
        tile[ty + r][tx] = v;
    }
    __syncthreads();
    for (int r = 0; r < 32; r += 8) {
        int ii = i0 + ty + r, jj = j0 + tx;
        if (ii < D1P && jj < D2) Wt[ii * D2 + jj] = tile[tx][ty + r];
    }
}

// ------------- fully parallel sparse z: one block per (t,b) ------------------
// 512 threads (8 waves); compact x[t][b][:] in-block, then each thread j sums
// Wt[i][j] over the active list. Massive TLP -> L2-BW-bound, no latency stall.
__global__ __launch_bounds__(512) void gather_z(
    const float* __restrict__ x,   // [STEPS][BATCH][D1]
    const float* __restrict__ Wt,  // [D1P][D2]
    float* __restrict__ z)         // [NSTEP][BATCH][D2]
{
    const int tb   = blockIdx.x;           // t*BATCH + b, t in [0,99)
    const int tid  = threadIdx.x;
    const int lane = tid & 63;

    __shared__ int s_cnt;
    __shared__ __align__(16) unsigned int s_off[LIST_MAX];

    if (tid == 0) s_cnt = 0;
    __syncthreads();

    const float* xt = x + (size_t)tb * D1;
    for (int base = 0; base < D1; base += 512) {
        int i = base + tid;
        bool a = (i < D1) && (xt[i] > 0.5f);
        unsigned long long m = __ballot(a);
        int n = __popcll(m);
        int pre = __popcll(m & ((1ull << lane) - 1ull));
        int wb = 0;
        if (lane == 0 && n) wb = atomicAdd(&s_cnt, n);
        wb = __shfl(wb, 0);
        if (a) {
            int p = wb + pre;
            if (p < LIST_MAX) s_off[p] = (unsigned int)(i << 11);  // byte offset
        }
    }
    __syncthreads();
    int cnt = s_cnt; if (cnt > LIST_MAX) cnt = LIST_MAX;
    int cnt8 = (cnt + 7) & ~7;
    if (tid < cnt8 - cnt) s_off[cnt + tid] = (unsigned int)(D1 << 11); // zero row
    __syncthreads();

    const char* wbase = (const char*)Wt;
    const unsigned int j4 = (unsigned int)(tid << 2);
    float a0 = 0.f, a1 = 0.f, a2 = 0.f, a3 = 0.f;
    float a4 = 0.f, a5 = 0.f, a6 = 0.f, a7 = 0.f;
    for (int k = 0; k < cnt8; k += 8) {
        uint4 o0 = *(const uint4*)(s_off + k);       // LDS broadcast
        uint4 o1 = *(const uint4*)(s_off + k + 4);
        a0 += *(const float*)(wbase + (o0.x + j4));
        a1 += *(const float*)(wbase + (o0.y + j4));
        a2 += *(const float*)(wbase + (o0.z + j4));
        a3 += *(const float*)(wbase + (o0.w + j4));
        a4 += *(const float*)(wbase + (o1.x + j4));
        a5 += *(const float*)(wbase + (o1.y + j4));
        a6 += *(const float*)(wbase + (o1.z + j4));
        a7 += *(const float*)(wbase + (o1.w + j4));
    }
    z[(size_t)tb * D2 + tid] = ((a0 + a1) + (a2 + a3)) + ((a4 + a5) + (a6 + a7));
}

// ------------- elementwise LIF scan over t (HBM-bound) -----------------------
__global__ __launch_bounds__(256) void lif_scan(
    const float* __restrict__ z, float* __restrict__ out)
{
    const int gid = blockIdx.x * 256 + threadIdx.x;   // b*D2 + j, 131072 total
    out[gid] = 0.f;                                   // step-0 row zeros
    float I = 0.f, V = 0.f;
    const float* zp = z + gid;
    float* op = out + (size_t)(BATCH * D2) + gid;
    for (int t0 = 0; t0 < NSTEP; t0 += 8) {
        const int n = (NSTEP - t0 < 8) ? (NSTEP - t0) : 8;
        float zz[8];
        #pragma unroll
        for (int u = 0; u < 8; ++u)
            if (u < n) zz[u] = zp[(size_t)(t0 + u) * (BATCH * D2)];
        #pragma unroll
        for (int u = 0; u < 8; ++u)
            if (u < n) {
                I = 0.8f * I + zz[u];
                float Vp = 0.95f * V + 0.05f * I;
                float s = (Vp > 1.0f) ? 1.0f : 0.f;
                V = (1.0f - s) * Vp;
                op[(size_t)(t0 + u) * (BATCH * D2)] = s;
            }
    }
}

// ===================== fallback path (R4 kernels) ============================
__global__ __launch_bounds__(256) void prep_kernel(
    const float* __restrict__ W, const float* __restrict__ x,
    float* __restrict__ Wt, unsigned int* __restrict__ lists,
    int* __restrict__ cnt8s)
{
    if (blockIdx.x < NBLK_T) {
        __shared__ float tile[32][33];
        int bt = blockIdx.x;
        int i0 = (bt % 25) * 32;
        int j0 = (bt / 25) * 32;
        int tx = threadIdx.x & 31, ty = threadIdx.x >> 5;
        for (int r = 0; r < 32; r += 8) {
            int jj = j0 + ty + r, ii = i0 + tx;
            float v = 0.f;
            if (jj < D2 && ii < D1) v = W[jj * D1 + ii];
            tile[ty + r][tx] = v;
        }
        __syncthreads();
        for (int r = 0; r < 32; r += 8) {
            int ii = i0 + ty + r, jj = j0 + tx;
            if (ii < D1P && jj < D2) Wt[ii * D2 + jj] = tile[tx][ty + r];
        }
        return;
    }
    const int wid = (blockIdx.x - NBLK_T) * 4 + (threadIdx.x >> 6);
    const int lane = threadIdx.x & 63;
    const float* xt = x + (size_t)wid * D1;
    unsigned int* lp = lists + (size_t)wid * LIST_PAD;
    int cnt = 0;
    for (int base = 0; base < D1; base += 64) {
        int i = base + lane;
        bool a = (i < D1) && (xt[i] > 0.5f);
        unsigned long long m = __ballot(a);
        int pre = __popcll(m & ((1ull << lane) - 1ull));
        if (a) {
            int p = cnt + pre;
            if (p < LIST_PAD) lp[p] = (unsigned int)(i << 11);
        }
        cnt += __popcll(m);
    }
    if (cnt > LIST_PAD) cnt = LIST_PAD;
    int cnt8 = (cnt + 7) & ~7;
    int p = cnt + lane;
    if (p < cnt8) lp[p] = (unsigned int)(D1 << 11);
    if (lane == 0) cnt8s[wid] = cnt8;
}

__global__ __launch_bounds__(256) void snn_main(
    const float* __restrict__ Wt, const unsigned int* __restrict__ lists,
    const int* __restrict__ cnt8s, float* __restrict__ out)
{
    const int b    = blockIdx.x >> 1;
    const int jh   = blockIdx.x & 1;
    const int wave = threadIdx.x >> 6;
    const int lane = threadIdx.x & 63;
    const int j    = jh * 256 + wave * 64 + lane;
    __shared__ __align__(16) unsigned int s_off[NSTEP * LIST_PAD];
    __shared__ int s_cnt[NSTEP + 1];
    for (int idx = threadIdx.x; idx < NSTEP * LIST_PAD; idx += 256) {
        int t = idx / LIST_PAD;
        int k = idx - t * LIST_PAD;
        s_off[idx] = lists[((size_t)t * BATCH + b) * LIST_PAD + k];
    }
    if (threadIdx.x < NSTEP) s_cnt[threadIdx.x] = cnt8s[threadIdx.x * BATCH + b];
    out[(size_t)b * D2 + jh * 256 + threadIdx.x] = 0.f;
    __syncthreads();
    const char* wbase = (const char*)Wt;
    const unsigned int j4 = (unsigned int)(j << 2);
    float I = 0.f, V = 0.f;
    for (int t = 0; t < NSTEP; ++t) {
        const unsigned int* lp = s_off + t * LIST_PAD;
        const int c8 = s_cnt[t];
        float a0 = 0.f, a1 = 0.f, a2 = 0.f, a3 = 0.f;
        float a4 = 0.f, a5 = 0.f, a6 = 0.f, a7 = 0.f;
        for (int k = 0; k < c8; k += 8) {
            uint4 o0 = *(const uint4*)(lp + k);
            uint4 o1 = *(const uint4*)(lp + k + 4);
            a0 += *(const float*)(wbase + (o0.x + j4));
            a1 += *(const float*)(wbase + (o0.y + j4));
            a2 += *(const float*)(wbase + (o0.z + j4));
            a3 += *(const float*)(wbase + (o0.w + j4));
            a4 += *(const float*)(wbase + (o1.x + j4));
            a5 += *(const float*)(wbase + (o1.y + j4));
            a6 += *(const float*)(wbase + (o1.z + j4));
            a7 += *(const float*)(wbase + (o1.w + j4));
        }
        float acc = ((a0 + a1) + (a2 + a3)) + ((a4 + a5) + (a6 + a7));
        I = 0.8f * I + acc;
        float Vp = 0.95f * V + 0.05f * I;
        float s = (Vp > 1.0f) ? 1.0f : 0.f;
        V = (1.0f - s) * Vp;
        out[(size_t)(t + 1) * (BATCH * D2) + (size_t)b * D2 + j] = s;
    }
}

__global__ __launch_bounds__(256) void snn_fallback(
    const float* __restrict__ x, const float* __restrict__ Wfull,
    float* __restrict__ out)
{
    const int b = blockIdx.x >> 1;
    const int jhalf = blockIdx.x & 1;
    const int j = jhalf * 256 + threadIdx.x;
    const int lane = threadIdx.x & 63;
    __shared__ int s_cnt;
    __shared__ int s_list[D1];
    out[(size_t)b * D2 + j] = 0.f;
    float I = 0.f, V = 0.f;
    const float* wrow = Wfull + (size_t)j * D1;
    for (int t = 0; t < STEPS - 1; ++t) {
        if (threadIdx.x == 0) s_cnt = 0;
        __syncthreads();
        const float* xt = x + (size_t)(t * BATCH + b) * D1;
        for (int base = 0; base < D1; base += 256) {
            int i = base + threadIdx.x;
            bool active = (i < D1) && (xt[i] > 0.5f);
            unsigned long long mask = __ballot(active);
            int nact = __popcll(mask);
            int pre = __popcll(mask & ((1ull << lane) - 1ull));
            int wb = 0;
            if (lane == 0 && nact) wb = atomicAdd(&s_cnt, nact);
            wb = __shfl(wb, 0);
            if (active) s_list[wb + pre] = i;
        }
        __syncthreads();
        const int cnt = s_cnt;
        float a0 = 0.f, a1 = 0.f, a2 = 0.f, a3 = 0.f;
        int k = 0;
        for (; k + 4 <= cnt; k += 4) {
            a0 += wrow[s_list[k]];     a1 += wrow[s_list[k + 1]];
            a2 += wrow[s_list[k + 2]]; a3 += wrow[s_list[k + 3]];
        }
        for (; k < cnt; ++k) a0 += wrow[s_list[k]];
        float acc = (a0 + a1) + (a2 + a3);
        I = 0.8f * I + acc;
        float Vp = 0.95f * V + 0.05f * I;
        float s = (Vp > 1.0f) ? 1.0f : 0.f;
        V = (1.0f - s) * Vp;
        out[(size_t)(t + 1) * (BATCH * D2) + (size_t)b * D2 + j] = s;
        __syncthreads();
    }
}

extern "C" void kernel_launch(void* const* d_in, const int* in_sizes, int n_in,
                              void* d_out, int out_size, void* d_ws, size_t ws_size,
                              hipStream_t stream) {
    const float* x = (const float*)d_in[0];   // [100][256][784]
    const float* w = (const float*)d_in[1];   // [512][784]
    float* out = (float*)d_out;               // [100][256][512]
    char* ws = (char*)d_ws;

    if (ws_size >= WS_NEEDED) {
        float* wt = (float*)ws;
        float* z  = (float*)(ws + Z_OFF);
        dim3 tg(25, 16), tb(32, 8);
        transpose_w<<<tg, tb, 0, stream>>>(w, wt);
        gather_z<<<NSTEP * BATCH, 512, 0, stream>>>(x, wt, z);
        lif_scan<<<BATCH * D2 / 256, 256, 0, stream>>>(z, out);
    } else if (ws_size >= WS_NEEDED_FB) {
        float* wt = (float*)ws;
        int* cnt8s = (int*)(ws + CNT_OFF);
        unsigned int* lists = (unsigned int*)(ws + LIST_OFF);
        prep_kernel<<<NBLK_T + NBLK_C, 256, 0, stream>>>(w, x, wt, lists, cnt8s);
        snn_main<<<BATCH * 2, 256, 0, stream>>>(wt, lists, cnt8s, out);
    } else {
        snn_fallback<<<BATCH * 2, 256, 0, stream>>>(x, w, out);
    }
}

// Round 6
// 240.761 us; speedup vs baseline: 1.0664x; 1.0664x over previous
//
#include <hip/hip_runtime.h>

#define STEPS 100
#define BATCH 256
#define D1 784
#define D1P 785            // +1 zero row = padding target for gathers
#define D2 512
#define NSTEP 99           // computed steps t = 0..98 (output rows 1..99)
#define HALF1 392          // half-row split for wave-private compaction
#define HCAP 64            // capacity per half; Binom(392,.05) max ~46

// ---- primary ws layout: Wt [D1P][D2] fp32 ++ z [NSTEP][BATCH][D2] fp32 ----
#define WT_BYTES  (D1P * D2 * 4)                       // 1,607,680
#define Z_OFF     ((size_t)((WT_BYTES + 255) & ~255))
#define Z_BYTES   ((size_t)NSTEP * BATCH * D2 * 4)     // 51,904,512
#define WS_NEEDED (Z_OFF + Z_BYTES)

// ---- fallback (R4) ws layout ----
#define LIST_PAD   80
#define NBLK_T     400
#define NBLK_C     (NSTEP * BATCH / 4)
#define CNT_OFF    WT_BYTES
#define CNT_BYTES  (NSTEP * BATCH * 4)
#define LIST_OFF   ((CNT_OFF + CNT_BYTES + 255) & ~255)
#define LIST_BYTES (NSTEP * BATCH * LIST_PAD * 4)
#define WS_NEEDED_FB ((size_t)(LIST_OFF + LIST_BYTES))

// ---------------- transpose W [D2][D1] -> Wt [D1P][D2], row 784 zeroed -------
__global__ void transpose_w(const float* __restrict__ W, float* __restrict__ Wt) {
    __shared__ float tile[32][33];
    int i0 = blockIdx.x * 32;
    int j0 = blockIdx.y * 32;
    int tx = threadIdx.x, ty = threadIdx.y;
    for (int r = 0; r < 32; r += 8) {
        int jj = j0 + ty + r, ii = i0 + tx;
        float v = 0.f;
        if (jj < D2 && ii < D1) v = W[jj * D1 + ii];
        tile[ty + r][tx] = v;
    }
    __syncthreads();
    for (int r = 0; r < 32; r += 8) {
        int ii = i0 + ty + r, jj = j0 + tx;
        if (ii < D1P && jj < D2) Wt[ii * D2 + jj] = tile[tx][ty + r];
    }
}

// ------------- parallel sparse z, wide gathers -------------------------------
// 512 thr = 4 groups x 128 thr (2 waves). Group g owns tb = blockIdx*4+g.
// Each wave privately compacts half the x-row (no atomics); after ONE barrier
// each thread gathers float4 (dwordx4) slices of Wt rows: 1 KB per wave-load.
__global__ __launch_bounds__(512) void gather_z(
    const float* __restrict__ x,   // [STEPS][BATCH][D1]
    const float* __restrict__ Wt,  // [D1P][D2]
    float* __restrict__ z)         // [NSTEP][BATCH][D2]
{
    const int g    = threadIdx.x >> 7;          // group 0..3
    const int t128 = threadIdx.x & 127;
    const int half = (threadIdx.x >> 6) & 1;    // wave within group
    const int lane = threadIdx.x & 63;
    const int tb   = blockIdx.x * 4 + g;        // t*BATCH + b

    __shared__ __align__(16) unsigned int s_off[4][2][HCAP];
    __shared__ int s_cnt[4][2];

    // wave-private ballot compaction of a 392-element half-row
    {
        const float* xh = x + (size_t)tb * D1 + half * HALF1;
        unsigned int* lp = s_off[g][half];
        int cnt = 0;
        for (int base = 0; base < HALF1; base += 64) {
            int i = base + lane;
            bool a = (i < HALF1) && (xh[i] > 0.5f);
            unsigned long long m = __ballot(a);
            int pre = __popcll(m & ((1ull << lane) - 1ull));
            if (a) {
                int p = cnt + pre;
                if (p < HCAP) lp[p] = (unsigned int)((half * HALF1 + i) << 11);
            }
            cnt += __popcll(m);
        }
        if (cnt > HCAP) cnt = HCAP;
        int cnt4 = (cnt + 3) & ~3;
        if (lane < cnt4 - cnt) lp[cnt + lane] = (unsigned int)(D1 << 11); // zero row
        if (lane == 0) s_cnt[g][half] = cnt4;
    }
    __syncthreads();

    const char* wj = (const char*)Wt + (t128 << 4);   // + j*4 (float4 slice)
    float ax0 = 0.f, ay0 = 0.f, az0 = 0.f, aw0 = 0.f;
    float ax1 = 0.f, ay1 = 0.f, az1 = 0.f, aw1 = 0.f;
    #pragma unroll
    for (int h = 0; h < 2; ++h) {
        const unsigned int* l = s_off[g][h];
        const int c4 = s_cnt[g][h];
        for (int k = 0; k < c4; k += 4) {
            uint4 o = *(const uint4*)(l + k);          // LDS broadcast b128
            float4 w0 = *(const float4*)(wj + o.x);    // global dwordx4
            float4 w1 = *(const float4*)(wj + o.y);
            float4 w2 = *(const float4*)(wj + o.z);
            float4 w3 = *(const float4*)(wj + o.w);
            ax0 += w0.x; ay0 += w0.y; az0 += w0.z; aw0 += w0.w;
            ax1 += w1.x; ay1 += w1.y; az1 += w1.z; aw1 += w1.w;
            ax0 += w2.x; ay0 += w2.y; az0 += w2.z; aw0 += w2.w;
            ax1 += w3.x; ay1 += w3.y; az1 += w3.z; aw1 += w3.w;
        }
    }
    float4 r;
    r.x = ax0 + ax1; r.y = ay0 + ay1; r.z = az0 + az1; r.w = aw0 + aw1;
    *(float4*)(z + (size_t)tb * D2 + (t128 << 2)) = r;
}

// ------------- elementwise LIF scan over t (HBM-bound) -----------------------
__global__ __launch_bounds__(256) void lif_scan(
    const float* __restrict__ z, float* __restrict__ out)
{
    const int gid = blockIdx.x * 256 + threadIdx.x;   // b*D2 + j, 131072 total
    out[gid] = 0.f;                                   // step-0 row zeros
    float I = 0.f, V = 0.f;
    const float* zp = z + gid;
    float* op = out + (size_t)(BATCH * D2) + gid;
    for (int t0 = 0; t0 < NSTEP; t0 += 8) {
        const int n = (NSTEP - t0 < 8) ? (NSTEP - t0) : 8;
        float zz[8];
        #pragma unroll
        for (int u = 0; u < 8; ++u)
            if (u < n) zz[u] = zp[(size_t)(t0 + u) * (BATCH * D2)];
        #pragma unroll
        for (int u = 0; u < 8; ++u)
            if (u < n) {
                I = 0.8f * I + zz[u];
                float Vp = 0.95f * V + 0.05f * I;
                float s = (Vp > 1.0f) ? 1.0f : 0.f;
                V = (1.0f - s) * Vp;
                op[(size_t)(t0 + u) * (BATCH * D2)] = s;
            }
    }
}

// ===================== fallback path (R4 kernels) ============================
__global__ __launch_bounds__(256) void prep_kernel(
    const float* __restrict__ W, const float* __restrict__ x,
    float* __restrict__ Wt, unsigned int* __restrict__ lists,
    int* __restrict__ cnt8s)
{
    if (blockIdx.x < NBLK_T) {
        __shared__ float tile[32][33];
        int bt = blockIdx.x;
        int i0 = (bt % 25) * 32;
        int j0 = (bt / 25) * 32;
        int tx = threadIdx.x & 31, ty = threadIdx.x >> 5;
        for (int r = 0; r < 32; r += 8) {
            int jj = j0 + ty + r, ii = i0 + tx;
            float v = 0.f;
            if (jj < D2 && ii < D1) v = W[jj * D1 + ii];
            tile[ty + r][tx] = v;
        }
        __syncthreads();
        for (int r = 0; r < 32; r += 8) {
            int ii = i0 + ty + r, jj = j0 + tx;
            if (ii < D1P && jj < D2) Wt[ii * D2 + jj] = tile[tx][ty + r];
        }
        return;
    }
    const int wid = (blockIdx.x - NBLK_T) * 4 + (threadIdx.x >> 6);
    const int lane = threadIdx.x & 63;
    const float* xt = x + (size_t)wid * D1;
    unsigned int* lp = lists + (size_t)wid * LIST_PAD;
    int cnt = 0;
    for (int base = 0; base < D1; base += 64) {
        int i = base + lane;
        bool a = (i < D1) && (xt[i] > 0.5f);
        unsigned long long m = __ballot(a);
        int pre = __popcll(m & ((1ull << lane) - 1ull));
        if (a) {
            int p = cnt + pre;
            if (p < LIST_PAD) lp[p] = (unsigned int)(i << 11);
        }
        cnt += __popcll(m);
    }
    if (cnt > LIST_PAD) cnt = LIST_PAD;
    int cnt8 = (cnt + 7) & ~7;
    int p = cnt + lane;
    if (p < cnt8) lp[p] = (unsigned int)(D1 << 11);
    if (lane == 0) cnt8s[wid] = cnt8;
}

__global__ __launch_bounds__(256) void snn_main(
    const float* __restrict__ Wt, const unsigned int* __restrict__ lists,
    const int* __restrict__ cnt8s, float* __restrict__ out)
{
    const int b    = blockIdx.x >> 1;
    const int jh   = blockIdx.x & 1;
    const int wave = threadIdx.x >> 6;
    const int lane = threadIdx.x & 63;
    const int j    = jh * 256 + wave * 64 + lane;
    __shared__ __align__(16) unsigned int s_off[NSTEP * LIST_PAD];
    __shared__ int s_cnt[NSTEP + 1];
    for (int idx = threadIdx.x; idx < NSTEP * LIST_PAD; idx += 256) {
        int t = idx / LIST_PAD;
        int k = idx - t * LIST_PAD;
        s_off[idx] = lists[((size_t)t * BATCH + b) * LIST_PAD + k];
    }
    if (threadIdx.x < NSTEP) s_cnt[threadIdx.x] = cnt8s[threadIdx.x * BATCH + b];
    out[(size_t)b * D2 + jh * 256 + threadIdx.x] = 0.f;
    __syncthreads();
    const char* wbase = (const char*)Wt;
    const unsigned int j4 = (unsigned int)(j << 2);
    float I = 0.f, V = 0.f;
    for (int t = 0; t < NSTEP; ++t) {
        const unsigned int* lp = s_off + t * LIST_PAD;
        const int c8 = s_cnt[t];
        float a0 = 0.f, a1 = 0.f, a2 = 0.f, a3 = 0.f;
        float a4 = 0.f, a5 = 0.f, a6 = 0.f, a7 = 0.f;
        for (int k = 0; k < c8; k += 8) {
            uint4 o0 = *(const uint4*)(lp + k);
            uint4 o1 = *(const uint4*)(lp + k + 4);
            a0 += *(const float*)(wbase + (o0.x + j4));
            a1 += *(const float*)(wbase + (o0.y + j4));
            a2 += *(const float*)(wbase + (o0.z + j4));
            a3 += *(const float*)(wbase + (o0.w + j4));
            a4 += *(const float*)(wbase + (o1.x + j4));
            a5 += *(const float*)(wbase + (o1.y + j4));
            a6 += *(const float*)(wbase + (o1.z + j4));
            a7 += *(const float*)(wbase + (o1.w + j4));
        }
        float acc = ((a0 + a1) + (a2 + a3)) + ((a4 + a5) + (a6 + a7));
        I = 0.8f * I + acc;
        float Vp = 0.95f * V + 0.05f * I;
        float s = (Vp > 1.0f) ? 1.0f : 0.f;
        V = (1.0f - s) * Vp;
        out[(size_t)(t + 1) * (BATCH * D2) + (size_t)b * D2 + j] = s;
    }
}

__global__ __launch_bounds__(256) void snn_fallback(
    const float* __restrict__ x, const float* __restrict__ Wfull,
    float* __restrict__ out)
{
    const int b = blockIdx.x >> 1;
    const int jhalf = blockIdx.x & 1;
    const int j = jhalf * 256 + threadIdx.x;
    const int lane = threadIdx.x & 63;
    __shared__ int s_cnt;
    __shared__ int s_list[D1];
    out[(size_t)b * D2 + j] = 0.f;
    float I = 0.f, V = 0.f;
    const float* wrow = Wfull + (size_t)j * D1;
    for (int t = 0; t < STEPS - 1; ++t) {
        if (threadIdx.x == 0) s_cnt = 0;
        __syncthreads();
        const float* xt = x + (size_t)(t * BATCH + b) * D1;
        for (int base = 0; base < D1; base += 256) {
            int i = base + threadIdx.x;
            bool active = (i < D1) && (xt[i] > 0.5f);
            unsigned long long mask = __ballot(active);
            int nact = __popcll(mask);
            int pre = __popcll(mask & ((1ull << lane) - 1ull));
            int wb = 0;
            if (lane == 0 && nact) wb = atomicAdd(&s_cnt, nact);
            wb = __shfl(wb, 0);
            if (active) s_list[wb + pre] = i;
        }
        __syncthreads();
        const int cnt = s_cnt;
        float a0 = 0.f, a1 = 0.f, a2 = 0.f, a3 = 0.f;
        int k = 0;
        for (; k + 4 <= cnt; k += 4) {
            a0 += wrow[s_list[k]];     a1 += wrow[s_list[k + 1]];
            a2 += wrow[s_list[k + 2]]; a3 += wrow[s_list[k + 3]];
        }
        for (; k < cnt; ++k) a0 += wrow[s_list[k]];
        float acc = (a0 + a1) + (a2 + a3);
        I = 0.8f * I + acc;
        float Vp = 0.95f * V + 0.05f * I;
        float s = (Vp > 1.0f) ? 1.0f : 0.f;
        V = (1.0f - s) * Vp;
        out[(size_t)(t + 1) * (BATCH * D2) + (size_t)b * D2 + j] = s;
        __syncthreads();
    }
}

extern "C" void kernel_launch(void* const* d_in, const int* in_sizes, int n_in,
                              void* d_out, int out_size, void* d_ws, size_t ws_size,
                              hipStream_t stream) {
    const float* x = (const float*)d_in[0];   // [100][256][784]
    const float* w = (const float*)d_in[1];   // [512][784]
    float* out = (float*)d_out;               // [100][256][512]
    char* ws = (char*)d_ws;

    if (ws_size >= WS_NEEDED) {
        float* wt = (float*)ws;
        float* z  = (float*)(ws + Z_OFF);
        dim3 tg(25, 16), tb(32, 8);
        transpose_w<<<tg, tb, 0, stream>>>(w, wt);
        gather_z<<<NSTEP * BATCH / 4, 512, 0, stream>>>(x, wt, z);
        lif_scan<<<BATCH * D2 / 256, 256, 0, stream>>>(z, out);
    } else if (ws_size >= WS_NEEDED_FB) {
        float* wt = (float*)ws;
        int* cnt8s = (int*)(ws + CNT_OFF);
        unsigned int* lists = (unsigned int*)(ws + LIST_OFF);
        prep_kernel<<<NBLK_T + NBLK_C, 256, 0, stream>>>(w, x, wt, lists, cnt8s);
        snn_main<<<BATCH * 2, 256, 0, stream>>>(wt, lists, cnt8s, out);
    } else {
        snn_fallback<<<BATCH * 2, 256, 0, stream>>>(x, w, out);
    }
}